// Round 1
// baseline (3104.271 us; speedup 1.0000x reference)
//
#include <hip/hip_runtime.h>
#include <hip/hip_bf16.h>
#include <math.h>

#define NL 4
#define DM 1024
#define DI 2048
#define DS 16
#define DR 64
#define DC 4
#define B_ 8
#define L_ 224
#define DLOC 672
#define NC 10
#define EPS 1e-5f

#define ROWS (B_ * L_)  // 1792

// ---------------------------------------------------------------------------
// Generic tiled fp32 GEMM: C[M,N] (+)= A[M,K] @ B[K,N] (+bias) (+softplus)
// BM=BN=64, BK=16, 256 threads, 4x4 microtile per thread.
// Requires: M % 64 == 0, K % 16 == 0. N arbitrary (guarded).
// ---------------------------------------------------------------------------
template <int ACC, int ACT>
__global__ __launch_bounds__(256) void gemm_kernel(
    const float* __restrict__ A, const float* __restrict__ Bm,
    const float* __restrict__ bias, float* __restrict__ C, int M, int N, int K,
    int lda, int ldb, int ldc) {
  __shared__ float As[16][64];  // As[k][m] (transposed)
  __shared__ float Bs[16][64];  // Bs[k][n]
  const int tid = threadIdx.x;
  const int tx = tid & 15;   // n direction
  const int ty = tid >> 4;   // m direction
  const int n0 = blockIdx.x * 64;
  const int m0 = blockIdx.y * 64;

  // A-tile load mapping: each thread loads A[m0+am][k0+ak .. k0+ak+3]
  const int am = tid & 63;
  const int ak = (tid >> 6) * 4;
  // B-tile load mapping: each thread loads B[k0+bk][n0+bn .. n0+bn+3]
  const int bk = tid >> 4;
  const int bn = (tid & 15) * 4;

  float acc[4][4];
#pragma unroll
  for (int i = 0; i < 4; i++)
#pragma unroll
    for (int j = 0; j < 4; j++) acc[i][j] = 0.f;

  for (int k0 = 0; k0 < K; k0 += 16) {
    float4 av = *(const float4*)(A + (size_t)(m0 + am) * lda + k0 + ak);
    float4 bv;
    {
      int n = n0 + bn;
      const float* bp = Bm + (size_t)(k0 + bk) * ldb + n;
      if (n + 3 < N) {
        bv = *(const float4*)bp;
      } else {
        bv.x = (n + 0 < N) ? bp[0] : 0.f;
        bv.y = (n + 1 < N) ? bp[1] : 0.f;
        bv.z = (n + 2 < N) ? bp[2] : 0.f;
        bv.w = (n + 3 < N) ? bp[3] : 0.f;
      }
    }
    __syncthreads();
    As[ak + 0][am] = av.x;
    As[ak + 1][am] = av.y;
    As[ak + 2][am] = av.z;
    As[ak + 3][am] = av.w;
    *(float4*)(&Bs[bk][bn]) = bv;
    __syncthreads();
#pragma unroll
    for (int kk = 0; kk < 16; kk++) {
      float4 a4 = *(const float4*)(&As[kk][ty * 4]);
      float4 b4 = *(const float4*)(&Bs[kk][tx * 4]);
      float ar[4] = {a4.x, a4.y, a4.z, a4.w};
      float br[4] = {b4.x, b4.y, b4.z, b4.w};
#pragma unroll
      for (int i = 0; i < 4; i++)
#pragma unroll
        for (int j = 0; j < 4; j++) acc[i][j] = fmaf(ar[i], br[j], acc[i][j]);
    }
  }

#pragma unroll
  for (int i = 0; i < 4; i++) {
    int m = m0 + ty * 4 + i;
#pragma unroll
    for (int j = 0; j < 4; j++) {
      int n = n0 + tx * 4 + j;
      if (n < N) {
        float v = acc[i][j];
        if (bias) v += bias[n];
        if (ACT == 1) v = (v > 20.f) ? v : log1pf(expf(v));  // softplus
        float* p = C + (size_t)m * ldc + n;
        if (ACC) v += *p;
        *p = v;
      }
    }
  }
}

// ---------------------------------------------------------------------------
// RMSNorm: out[r,:] = h[r,:] * rsqrt(mean(h[r,:]^2)+eps) * w[:]
// one block (256 thr) per row, 4 elems/thread (DM=1024)
// ---------------------------------------------------------------------------
__global__ __launch_bounds__(256) void rmsnorm_kernel(
    const float* __restrict__ h, const float* __restrict__ w,
    float* __restrict__ out) {
  const int row = blockIdx.x;
  const int tid = threadIdx.x;
  const float4 v = *(const float4*)(h + (size_t)row * DM + tid * 4);
  float ss = v.x * v.x + v.y * v.y + v.z * v.z + v.w * v.w;
#pragma unroll
  for (int off = 32; off > 0; off >>= 1) ss += __shfl_xor(ss, off);
  __shared__ float red[4];
  if ((tid & 63) == 0) red[tid >> 6] = ss;
  __syncthreads();
  float tot = red[0] + red[1] + red[2] + red[3];
  const float inv = rsqrtf(tot / (float)DM + EPS);
  const float4 wv = *(const float4*)(w + tid * 4);
  float4 o;
  o.x = v.x * inv * wv.x;
  o.y = v.y * inv * wv.y;
  o.z = v.z * inv * wv.z;
  o.w = v.w * inv * wv.w;
  *(float4*)(out + (size_t)row * DM + tid * 4) = o;
}

// ---------------------------------------------------------------------------
// Causal depthwise conv (DC=4) + bias + silu.
// xp = xz[..., :DI] (row stride 2*DI). xc[b,t,d] row-major (B,L,DI).
// ---------------------------------------------------------------------------
__global__ __launch_bounds__(256) void conv_silu_kernel(
    const float* __restrict__ xz, const float* __restrict__ wc,
    const float* __restrict__ bc, float* __restrict__ xc) {
  const int idx = blockIdx.x * 256 + threadIdx.x;  // over B*L*DI
  const int d = idx & (DI - 1);
  const int t = (idx / DI) % L_;
  const int b = idx / (DI * L_);
  const float w0 = wc[d * 4 + 0], w1 = wc[d * 4 + 1], w2 = wc[d * 4 + 2],
              w3 = wc[d * 4 + 3];
  const size_t base = ((size_t)b * L_ + t) * (2 * DI) + d;
  float s = bc[d];
  if (t >= 3) s += xz[base - 3 * (2 * DI)] * w0;
  if (t >= 2) s += xz[base - 2 * (2 * DI)] * w1;
  if (t >= 1) s += xz[base - 1 * (2 * DI)] * w2;
  s += xz[base] * w3;
  s = s / (1.f + expf(-s));  // silu
  xc[idx] = s;
}

// ---------------------------------------------------------------------------
// Selective-scan: one wave per (b, 4-channel group). lane = (d_sub<<4)|s.
// Fuses the epilogue: y = (scan_y + Dp*xc) * silu(z)
// ---------------------------------------------------------------------------
__global__ __launch_bounds__(256) void scan_kernel(
    const float* __restrict__ dt, const float* __restrict__ xc,
    const float* __restrict__ xdbl, const float* __restrict__ xz,
    const float* __restrict__ A_log, const float* __restrict__ Dp,
    float* __restrict__ y) {
  const int tid = threadIdx.x;
  const int lane = tid & 63;
  const int w = blockIdx.x * 4 + (tid >> 6);  // global wave id 0..4095
  const int b = w >> 9;                       // / 512
  const int dg = w & 511;
  const int s = lane & 15;
  const int d = dg * 4 + (lane >> 4);

  const float A = -expf(A_log[d * DS + s]);
  const float Dpd = Dp[d];
  float hs = 0.f;
  const size_t rowBase = (size_t)b * L_;
  for (int t = 0; t < L_; t++) {
    const size_t r = rowBase + t;
    const float dtv = dt[r * DI + d];
    const float u = xc[r * DI + d];
    const float Bv = xdbl[r * 96 + DR + s];
    const float Cv = xdbl[r * 96 + DR + DS + s];
    const float dA = expf(dtv * A);
    hs = dA * hs + (dtv * u) * Bv;
    float p = hs * Cv;
    p += __shfl_xor(p, 8);
    p += __shfl_xor(p, 4);
    p += __shfl_xor(p, 2);
    p += __shfl_xor(p, 1);
    if (s == 0) {
      const float zv = xz[r * (2 * DI) + DI + d];
      float yv = p + Dpd * u;
      yv *= zv / (1.f + expf(-zv));  // * silu(z)
      y[r * DI + d] = yv;
    }
  }
}

// ---------------------------------------------------------------------------
// Final: rmsnorm(h[b, L-1, :]) @ w_fc + b_fc  -> out[b, 0..9]
// ---------------------------------------------------------------------------
__global__ __launch_bounds__(256) void final_kernel(
    const float* __restrict__ h, const float* __restrict__ fnw,
    const float* __restrict__ w_fc, const float* __restrict__ b_fc,
    float* __restrict__ out) {
  const int b = blockIdx.x;
  const int tid = threadIdx.x;
  const size_t row = ((size_t)b * L_ + (L_ - 1)) * DM;
  const float4 v = *(const float4*)(h + row + tid * 4);
  float ss = v.x * v.x + v.y * v.y + v.z * v.z + v.w * v.w;
#pragma unroll
  for (int off = 32; off > 0; off >>= 1) ss += __shfl_xor(ss, off);
  __shared__ float red[4];
  if ((tid & 63) == 0) red[tid >> 6] = ss;
  __syncthreads();
  float tot = red[0] + red[1] + red[2] + red[3];
  const float inv = rsqrtf(tot / (float)DM + EPS);
  const float4 wv = *(const float4*)(fnw + tid * 4);
  float hn[4] = {v.x * inv * wv.x, v.y * inv * wv.y, v.z * inv * wv.z,
                 v.w * inv * wv.w};
  float partial[NC];
#pragma unroll
  for (int j = 0; j < NC; j++) partial[j] = 0.f;
#pragma unroll
  for (int e = 0; e < 4; e++) {
    const int dd = tid * 4 + e;
#pragma unroll
    for (int j = 0; j < NC; j++)
      partial[j] = fmaf(hn[e], w_fc[dd * NC + j], partial[j]);
  }
  __shared__ float red2[256][NC];
  for (int j = 0; j < NC; j++) red2[tid][j] = partial[j];
  __syncthreads();
  for (int stride = 128; stride > 0; stride >>= 1) {
    if (tid < stride)
      for (int j = 0; j < NC; j++) red2[tid][j] += red2[tid + stride][j];
    __syncthreads();
  }
  if (tid < NC) out[b * NC + tid] = red2[0][tid] + b_fc[tid];
}

// ---------------------------------------------------------------------------
extern "C" void kernel_launch(void* const* d_in, const int* in_sizes, int n_in,
                              void* d_out, int out_size, void* d_ws,
                              size_t ws_size, hipStream_t stream) {
  const float* x = (const float*)d_in[0];
  const float* w_proj = (const float*)d_in[1];
  const float* b_proj = (const float*)d_in[2];
  const float* norm_w = (const float*)d_in[3];
  const float* w_in = (const float*)d_in[4];
  const float* w_conv = (const float*)d_in[5];
  const float* b_conv = (const float*)d_in[6];
  const float* w_x = (const float*)d_in[7];
  const float* w_dt = (const float*)d_in[8];
  const float* b_dt = (const float*)d_in[9];
  const float* A_log = (const float*)d_in[10];
  const float* Dp = (const float*)d_in[11];
  const float* w_out = (const float*)d_in[12];
  const float* fnw = (const float*)d_in[13];
  const float* w_fc = (const float*)d_in[14];
  const float* b_fc = (const float*)d_in[15];
  float* out = (float*)d_out;

  // Workspace layout (floats). xn aliased onto y (live ranges disjoint:
  // xn is consumed by the w_in GEMM before scan writes y; next layer's
  // rmsnorm runs after w_out consumed y).
  float* ws = (float*)d_ws;
  float* h = ws;                   // 1,835,008  (B*L*DM)
  float* xz = h + 1835008;         // 7,340,032  (B*L*2DI)
  float* xc = xz + 7340032;        // 3,670,016  (B*L*DI)
  float* xdbl = xc + 3670016;      // 172,032    (B*L*96)
  float* dt = xdbl + 172032;       // 3,670,016  (B*L*DI)
  float* y = dt + 3670016;         // 3,670,016  (B*L*DI)  [also xn]
  float* xn = y;

  const dim3 blk(256);

  // h = x @ w_proj + b_proj   (M=1792, N=1024, K=672)
  gemm_kernel<0, 0><<<dim3(1024 / 64, ROWS / 64), blk, 0, stream>>>(
      x, w_proj, b_proj, h, ROWS, DM, DLOC, DLOC, DM, DM);

  for (int l = 0; l < NL; l++) {
    // xn = rmsnorm(h) * norm_w[l]
    rmsnorm_kernel<<<ROWS, blk, 0, stream>>>(h, norm_w + (size_t)l * DM, xn);
    // xz = xn @ w_in[l]   (N=4096, K=1024)
    gemm_kernel<0, 0><<<dim3(2 * DI / 64, ROWS / 64), blk, 0, stream>>>(
        xn, w_in + (size_t)l * DM * 2 * DI, nullptr, xz, ROWS, 2 * DI, DM, DM,
        2 * DI, 2 * DI);
    // xc = silu(causal_conv(xp) + b_conv)
    conv_silu_kernel<<<ROWS * DI / 256, blk, 0, stream>>>(
        xz, w_conv + (size_t)l * DI * DC, b_conv + (size_t)l * DI, xc);
    // xdbl = xc @ w_x[l]   (N=96, K=2048)
    gemm_kernel<0, 0><<<dim3(2, ROWS / 64), blk, 0, stream>>>(
        xc, w_x + (size_t)l * DI * 96, nullptr, xdbl, ROWS, 96, DI, DI, 96,
        96);
    // dt = softplus(dtr @ w_dt[l] + b_dt[l])   (N=2048, K=64, lda=96)
    gemm_kernel<0, 1><<<dim3(DI / 64, ROWS / 64), blk, 0, stream>>>(
        xdbl, w_dt + (size_t)l * DR * DI, b_dt + (size_t)l * DI, dt, ROWS, DI,
        DR, 96, DI, DI);
    // y = scan(...) fused with (+Dp*xc)*silu(z)
    scan_kernel<<<(B_ * (DI / 4)) / 4, blk, 0, stream>>>(
        dt, xc, xdbl, xz, A_log + (size_t)l * DI * DS, Dp + (size_t)l * DI, y);
    // h += y @ w_out[l]   (N=1024, K=2048)
    gemm_kernel<1, 0><<<dim3(DM / 64, ROWS / 64), blk, 0, stream>>>(
        y, w_out + (size_t)l * DI * DM, nullptr, h, ROWS, DM, DI, DI, DM, DM);
  }

  // out = rmsnorm(h)[:, -1, :] @ w_fc + b_fc
  final_kernel<<<B_, blk, 0, stream>>>(h, fnw, w_fc, b_fc, out);
}

// Round 2
// 1650.765 us; speedup vs baseline: 1.8805x; 1.8805x over previous
//
#include <hip/hip_runtime.h>
#include <hip/hip_bf16.h>
#include <math.h>

#define NL 4
#define DM 1024
#define DI 2048
#define DS 16
#define DR 64
#define DC 4
#define B_ 8
#define L_ 224
#define DLOC 672
#define NC 10
#define EPS 1e-5f

#define ROWS (B_ * L_)  // 1792

typedef unsigned short u16;
typedef __attribute__((ext_vector_type(8))) short bf16x8;
typedef __attribute__((ext_vector_type(4))) float f32x4;
typedef __attribute__((address_space(1))) const void gvoid_t;
typedef __attribute__((address_space(3))) void lvoid_t;

__device__ __forceinline__ u16 f2bf(float f) {
  union { float f; unsigned int u; } v;
  v.f = f;
  unsigned int u = v.u;
  return (u16)((u + 0x7fffu + ((u >> 16) & 1u)) >> 16);  // RNE
}

// ---------------------------------------------------------------------------
// bf16 MFMA GEMM (m97 structure): C[M,N] (+)= A[M,K]_bf16 @ B, with B given
// TRANSPOSED: Bt[N,K]_bf16. Tiles: 128x128 per block (256 thr = 4 waves,
// each wave 64x64 = 4x4 MFMA 16x16x32). Staging via global_load_lds width=16.
// Requires M%128==0, N%128==0, K%32==0.
// ---------------------------------------------------------------------------
template <int ACC, int BIAS>
__global__ __launch_bounds__(256) void gemm_bt_mfma(
    const u16* __restrict__ A, const u16* __restrict__ Bt,
    const float* __restrict__ bias, float* __restrict__ C, int K, int lda,
    int ldb, int ldc) {
  __shared__ __align__(16) u16 As[128 * 32];
  __shared__ __align__(16) u16 Bs[128 * 32];
  const int tid = threadIdx.x;
  const int lane = tid & 63;
  const int wv = tid >> 6;
  const int n0 = blockIdx.x * 128;
  const int m0 = blockIdx.y * 128;
  const int wm0 = (wv & 1) * 64;
  const int wn0 = (wv >> 1) * 64;
  const int quad = lane >> 4;
  const int l16 = lane & 15;

  // staging mapping: 4 lanes per 32-elem (64B) row, 16 rows per instruction
  const int srow = wv * 32 + (lane >> 2);
  const int scol = (lane & 3) * 8;
  const u16* ga0 = A + (size_t)(m0 + srow) * lda + scol;
  const u16* ga1 = ga0 + (size_t)16 * lda;
  const u16* gb0 = Bt + (size_t)(n0 + srow) * ldb + scol;
  const u16* gb1 = gb0 + (size_t)16 * ldb;
  u16* la0 = &As[(wv * 32) * 32];
  u16* la1 = &As[(wv * 32 + 16) * 32];
  u16* lb0 = &Bs[(wv * 32) * 32];
  u16* lb1 = &Bs[(wv * 32 + 16) * 32];

  f32x4 acc[4][4] = {};

  for (int k0 = 0; k0 < K; k0 += 32) {
    __syncthreads();
    __builtin_amdgcn_global_load_lds((gvoid_t*)ga0, (lvoid_t*)la0, 16, 0, 0);
    __builtin_amdgcn_global_load_lds((gvoid_t*)ga1, (lvoid_t*)la1, 16, 0, 0);
    __builtin_amdgcn_global_load_lds((gvoid_t*)gb0, (lvoid_t*)lb0, 16, 0, 0);
    __builtin_amdgcn_global_load_lds((gvoid_t*)gb1, (lvoid_t*)lb1, 16, 0, 0);
    __syncthreads();
    bf16x8 af[4], bfr[4];
#pragma unroll
    for (int i = 0; i < 4; i++)
      af[i] = *(const bf16x8*)&As[(wm0 + i * 16 + l16) * 32 + quad * 8];
#pragma unroll
    for (int j = 0; j < 4; j++)
      bfr[j] = *(const bf16x8*)&Bs[(wn0 + j * 16 + l16) * 32 + quad * 8];
#pragma unroll
    for (int i = 0; i < 4; i++)
#pragma unroll
      for (int j = 0; j < 4; j++)
        acc[i][j] = __builtin_amdgcn_mfma_f32_16x16x32_bf16(af[i], bfr[j],
                                                            acc[i][j], 0, 0, 0);
    ga0 += 32; ga1 += 32; gb0 += 32; gb1 += 32;
  }

#pragma unroll
  for (int i = 0; i < 4; i++) {
#pragma unroll
    for (int j = 0; j < 4; j++) {
      const int col = n0 + wn0 + j * 16 + l16;
      const int rowb = m0 + wm0 + i * 16 + quad * 4;
      float bv = 0.f;
      if (BIAS) bv = bias[col];
#pragma unroll
      for (int r = 0; r < 4; r++) {
        float v = acc[i][j][r] + bv;
        float* p = C + (size_t)(rowb + r) * ldc + col;
        if (ACC) v += *p;
        *p = v;
      }
    }
  }
}

// ---------------------------------------------------------------------------
// fp32 tiled GEMM (kept for w_x split-K and dt). ACC: 0=store, 1=+=, 2=atomic.
// SPLITK: blockIdx.z selects a 256-wide K chunk.
// ---------------------------------------------------------------------------
template <int ACC, int ACT, int SPLITK>
__global__ __launch_bounds__(256) void gemm_kernel(
    const float* __restrict__ A, const float* __restrict__ Bm,
    const float* __restrict__ bias, float* __restrict__ C, int M, int N, int K,
    int lda, int ldb, int ldc) {
  if (SPLITK) {
    A += (size_t)blockIdx.z * 256;
    Bm += (size_t)blockIdx.z * 256 * ldb;
  }
  __shared__ float As[16][64];
  __shared__ float Bs[16][64];
  const int tid = threadIdx.x;
  const int tx = tid & 15;
  const int ty = tid >> 4;
  const int n0 = blockIdx.x * 64;
  const int m0 = blockIdx.y * 64;
  const int am = tid & 63;
  const int ak = (tid >> 6) * 4;
  const int bk = tid >> 4;
  const int bn = (tid & 15) * 4;

  float acc[4][4];
#pragma unroll
  for (int i = 0; i < 4; i++)
#pragma unroll
    for (int j = 0; j < 4; j++) acc[i][j] = 0.f;

  for (int k0 = 0; k0 < K; k0 += 16) {
    float4 av = *(const float4*)(A + (size_t)(m0 + am) * lda + k0 + ak);
    float4 bv;
    {
      int n = n0 + bn;
      const float* bp = Bm + (size_t)(k0 + bk) * ldb + n;
      if (n + 3 < N) {
        bv = *(const float4*)bp;
      } else {
        bv.x = (n + 0 < N) ? bp[0] : 0.f;
        bv.y = (n + 1 < N) ? bp[1] : 0.f;
        bv.z = (n + 2 < N) ? bp[2] : 0.f;
        bv.w = (n + 3 < N) ? bp[3] : 0.f;
      }
    }
    __syncthreads();
    As[ak + 0][am] = av.x;
    As[ak + 1][am] = av.y;
    As[ak + 2][am] = av.z;
    As[ak + 3][am] = av.w;
    *(float4*)(&Bs[bk][bn]) = bv;
    __syncthreads();
#pragma unroll
    for (int kk = 0; kk < 16; kk++) {
      float4 a4 = *(const float4*)(&As[kk][ty * 4]);
      float4 b4 = *(const float4*)(&Bs[kk][tx * 4]);
      float ar[4] = {a4.x, a4.y, a4.z, a4.w};
      float br[4] = {b4.x, b4.y, b4.z, b4.w};
#pragma unroll
      for (int i = 0; i < 4; i++)
#pragma unroll
        for (int j = 0; j < 4; j++) acc[i][j] = fmaf(ar[i], br[j], acc[i][j]);
    }
  }

#pragma unroll
  for (int i = 0; i < 4; i++) {
    int m = m0 + ty * 4 + i;
#pragma unroll
    for (int j = 0; j < 4; j++) {
      int n = n0 + tx * 4 + j;
      if (n < N) {
        float v = acc[i][j];
        if (bias) v += bias[n];
        if (ACT == 1) v = (v > 20.f) ? v : log1pf(expf(v));  // softplus
        float* p = C + (size_t)m * ldc + n;
        if (ACC == 2) {
          atomicAdd(p, v);
        } else {
          if (ACC == 1) v += *p;
          *p = v;
        }
      }
    }
  }
}

// ---------------------------------------------------------------------------
// fp32 [K,N] -> bf16 [N,K] transpose+convert, 32x32 LDS tiles
// ---------------------------------------------------------------------------
__global__ __launch_bounds__(256) void transpose_cvt_kernel(
    const float* __restrict__ src, u16* __restrict__ dst, int K, int N) {
  __shared__ float t[32][33];
  const int n0 = blockIdx.x * 32;
  const int k0 = blockIdx.y * 32;
  const int c = threadIdx.x & 31;
  const int r = threadIdx.x >> 5;  // 0..7
#pragma unroll
  for (int rr = 0; rr < 4; rr++)
    t[r + rr * 8][c] = src[(size_t)(k0 + r + rr * 8) * N + n0 + c];
  __syncthreads();
#pragma unroll
  for (int rr = 0; rr < 4; rr++)
    dst[(size_t)(n0 + r + rr * 8) * K + k0 + c] = f2bf(t[c][r + rr * 8]);
}

// flat fp32 -> bf16, 4 elems/thread
__global__ __launch_bounds__(256) void cvt_kernel(const float* __restrict__ src,
                                                  u16* __restrict__ dst) {
  const int i = blockIdx.x * 256 + threadIdx.x;
  const float4 v = ((const float4*)src)[i];
  ushort4 o;
  o.x = f2bf(v.x);
  o.y = f2bf(v.y);
  o.z = f2bf(v.z);
  o.w = f2bf(v.w);
  ((ushort4*)dst)[i] = o;
}

// ---------------------------------------------------------------------------
// RMSNorm -> bf16 out
// ---------------------------------------------------------------------------
__global__ __launch_bounds__(256) void rmsnorm_kernel(
    const float* __restrict__ h, const float* __restrict__ w,
    u16* __restrict__ out) {
  const int row = blockIdx.x;
  const int tid = threadIdx.x;
  const float4 v = *(const float4*)(h + (size_t)row * DM + tid * 4);
  float ss = v.x * v.x + v.y * v.y + v.z * v.z + v.w * v.w;
#pragma unroll
  for (int off = 32; off > 0; off >>= 1) ss += __shfl_xor(ss, off);
  __shared__ float red[4];
  if ((tid & 63) == 0) red[tid >> 6] = ss;
  __syncthreads();
  float tot = red[0] + red[1] + red[2] + red[3];
  const float inv = rsqrtf(tot / (float)DM + EPS);
  const float4 wv = *(const float4*)(w + tid * 4);
  ushort4 o;
  o.x = f2bf(v.x * inv * wv.x);
  o.y = f2bf(v.y * inv * wv.y);
  o.z = f2bf(v.z * inv * wv.z);
  o.w = f2bf(v.w * inv * wv.w);
  *(ushort4*)(out + (size_t)row * DM + tid * 4) = o;
}

// ---------------------------------------------------------------------------
// Causal depthwise conv (DC=4) + bias + silu (fp32 in/out)
// ---------------------------------------------------------------------------
__global__ __launch_bounds__(256) void conv_silu_kernel(
    const float* __restrict__ xz, const float* __restrict__ wc,
    const float* __restrict__ bc, float* __restrict__ xc) {
  const int idx = blockIdx.x * 256 + threadIdx.x;
  const int d = idx & (DI - 1);
  const int t = (idx / DI) % L_;
  const float w0 = wc[d * 4 + 0], w1 = wc[d * 4 + 1], w2 = wc[d * 4 + 2],
              w3 = wc[d * 4 + 3];
  const size_t base = (size_t)(idx / DI) * (2 * DI) + d;  // row r = idx/DI
  float s = bc[d];
  if (t >= 3) s += xz[base - 3 * (2 * DI)] * w0;
  if (t >= 2) s += xz[base - 2 * (2 * DI)] * w1;
  if (t >= 1) s += xz[base - 1 * (2 * DI)] * w2;
  s += xz[base] * w3;
  s = s / (1.f + expf(-s));
  xc[idx] = s;
}

// ---------------------------------------------------------------------------
// Selective scan, fused epilogue; y out as bf16
// ---------------------------------------------------------------------------
__global__ __launch_bounds__(256) void scan_kernel(
    const float* __restrict__ dt, const float* __restrict__ xc,
    const float* __restrict__ xdbl, const float* __restrict__ xz,
    const float* __restrict__ A_log, const float* __restrict__ Dp,
    u16* __restrict__ y) {
  const int tid = threadIdx.x;
  const int lane = tid & 63;
  const int w = blockIdx.x * 4 + (tid >> 6);
  const int b = w >> 9;
  const int dg = w & 511;
  const int s = lane & 15;
  const int d = dg * 4 + (lane >> 4);

  const float A = -expf(A_log[d * DS + s]);
  const float Dpd = Dp[d];
  float hs = 0.f;
  const size_t rowBase = (size_t)b * L_;
  for (int t = 0; t < L_; t++) {
    const size_t r = rowBase + t;
    const float dtv = dt[r * DI + d];
    const float u = xc[r * DI + d];
    const float Bv = xdbl[r * 96 + DR + s];
    const float Cv = xdbl[r * 96 + DR + DS + s];
    const float dA = expf(dtv * A);
    hs = dA * hs + (dtv * u) * Bv;
    float p = hs * Cv;
    p += __shfl_xor(p, 8);
    p += __shfl_xor(p, 4);
    p += __shfl_xor(p, 2);
    p += __shfl_xor(p, 1);
    if (s == 0) {
      const float zv = xz[r * (2 * DI) + DI + d];
      float yv = p + Dpd * u;
      yv *= zv / (1.f + expf(-zv));
      y[r * DI + d] = f2bf(yv);
    }
  }
}

// ---------------------------------------------------------------------------
// Final: rmsnorm(h[b, L-1, :]) @ w_fc + b_fc
// ---------------------------------------------------------------------------
__global__ __launch_bounds__(256) void final_kernel(
    const float* __restrict__ h, const float* __restrict__ fnw,
    const float* __restrict__ w_fc, const float* __restrict__ b_fc,
    float* __restrict__ out) {
  const int b = blockIdx.x;
  const int tid = threadIdx.x;
  const size_t row = ((size_t)b * L_ + (L_ - 1)) * DM;
  const float4 v = *(const float4*)(h + row + tid * 4);
  float ss = v.x * v.x + v.y * v.y + v.z * v.z + v.w * v.w;
#pragma unroll
  for (int off = 32; off > 0; off >>= 1) ss += __shfl_xor(ss, off);
  __shared__ float red[4];
  if ((tid & 63) == 0) red[tid >> 6] = ss;
  __syncthreads();
  float tot = red[0] + red[1] + red[2] + red[3];
  const float inv = rsqrtf(tot / (float)DM + EPS);
  const float4 wv = *(const float4*)(fnw + tid * 4);
  float hn[4] = {v.x * inv * wv.x, v.y * inv * wv.y, v.z * inv * wv.z,
                 v.w * inv * wv.w};
  float partial[NC];
#pragma unroll
  for (int j = 0; j < NC; j++) partial[j] = 0.f;
#pragma unroll
  for (int e = 0; e < 4; e++) {
    const int dd = tid * 4 + e;
#pragma unroll
    for (int j = 0; j < NC; j++)
      partial[j] = fmaf(hn[e], w_fc[dd * NC + j], partial[j]);
  }
  __shared__ float red2[256][NC];
  for (int j = 0; j < NC; j++) red2[tid][j] = partial[j];
  __syncthreads();
  for (int stride = 128; stride > 0; stride >>= 1) {
    if (tid < stride)
      for (int j = 0; j < NC; j++) red2[tid][j] += red2[tid + stride][j];
    __syncthreads();
  }
  if (tid < NC) out[b * NC + tid] = red2[0][tid] + b_fc[tid];
}

// ---------------------------------------------------------------------------
extern "C" void kernel_launch(void* const* d_in, const int* in_sizes, int n_in,
                              void* d_out, int out_size, void* d_ws,
                              size_t ws_size, hipStream_t stream) {
  const float* x = (const float*)d_in[0];
  const float* w_proj = (const float*)d_in[1];
  const float* b_proj = (const float*)d_in[2];
  const float* norm_w = (const float*)d_in[3];
  const float* w_in = (const float*)d_in[4];
  const float* w_conv = (const float*)d_in[5];
  const float* b_conv = (const float*)d_in[6];
  const float* w_x = (const float*)d_in[7];
  const float* w_dt = (const float*)d_in[8];
  const float* b_dt = (const float*)d_in[9];
  const float* A_log = (const float*)d_in[10];
  const float* Dp = (const float*)d_in[11];
  const float* w_out = (const float*)d_in[12];
  const float* fnw = (const float*)d_in[13];
  const float* w_fc = (const float*)d_in[14];
  const float* b_fc = (const float*)d_in[15];
  float* out = (float*)d_out;

  // Workspace layout (float units)
  float* ws = (float*)d_ws;
  float* h = ws;                       // 1,835,008 f
  float* xz = h + 1835008;             // 7,340,032 f
  float* xc = xz + 7340032;            // 3,670,016 f
  float* xdbl = xc + 3670016;          //   172,032 f
  float* dt = xdbl + 172032;           // 3,670,016 f
  u16* y16 = (u16*)(dt + 3670016);     // 3,670,016 bf16 (1,835,008 f)
  u16* xn16 = y16;                     // alias (disjoint liveness)
  u16* x16 = (u16*)(dt + 3670016 + 1835008);      // 1,204,224 bf16 (602,112 f)
  u16* wprojT = (u16*)(dt + 3670016 + 2437120);   //   688,128 bf16 (344,064 f)
  u16* winT = (u16*)(dt + 3670016 + 2781184);     // 4,194,304 bf16 (2,097,152 f)
  u16* woutT = (u16*)(dt + 3670016 + 4878336);    // 2,097,152 bf16 (1,048,576 f)

  const dim3 blk(256);

  // convert x -> bf16; w_proj -> bf16^T
  cvt_kernel<<<ROWS * DLOC / 1024, blk, 0, stream>>>(x, x16);
  transpose_cvt_kernel<<<dim3(DM / 32, DLOC / 32), blk, 0, stream>>>(
      w_proj, wprojT, DLOC, DM);

  // h = x @ w_proj + b_proj (bf16 MFMA): grid (N/128, M/128)
  gemm_bt_mfma<0, 1><<<dim3(DM / 128, ROWS / 128), blk, 0, stream>>>(
      x16, wprojT, b_proj, h, DLOC, DLOC, DLOC, DM);

  for (int l = 0; l < NL; l++) {
    // weight conversions for this layer
    transpose_cvt_kernel<<<dim3(2 * DI / 32, DM / 32), blk, 0, stream>>>(
        w_in + (size_t)l * DM * 2 * DI, winT, DM, 2 * DI);
    transpose_cvt_kernel<<<dim3(DM / 32, DI / 32), blk, 0, stream>>>(
        w_out + (size_t)l * DI * DM, woutT, DI, DM);

    // xn = rmsnorm(h) -> bf16
    rmsnorm_kernel<<<ROWS, blk, 0, stream>>>(h, norm_w + (size_t)l * DM, xn16);
    // xz = xn @ w_in[l]  (MFMA, N=4096, K=1024)
    gemm_bt_mfma<0, 0><<<dim3(2 * DI / 128, ROWS / 128), blk, 0, stream>>>(
        xn16, winT, nullptr, xz, DM, DM, DM, 2 * DI);
    // xc = silu(conv(xp) + b_conv)
    conv_silu_kernel<<<ROWS * DI / 256, blk, 0, stream>>>(
        xz, w_conv + (size_t)l * DI * DC, b_conv + (size_t)l * DI, xc);
    // xdbl = xc @ w_x[l]  (fp32 split-K x8 + atomics; zero first)
    hipMemsetAsync(xdbl, 0, (size_t)ROWS * 96 * sizeof(float), stream);
    gemm_kernel<2, 0, 1><<<dim3(2, ROWS / 64, 8), blk, 0, stream>>>(
        xc, w_x + (size_t)l * DI * 96, nullptr, xdbl, ROWS, 96, 256, DI, 96,
        96);
    // dt = softplus(dtr @ w_dt[l] + b_dt[l])  (fp32, K=64)
    gemm_kernel<0, 1, 0><<<dim3(DI / 64, ROWS / 64), blk, 0, stream>>>(
        xdbl, w_dt + (size_t)l * DR * DI, b_dt + (size_t)l * DI, dt, ROWS, DI,
        DR, 96, DI, DI);
    // y = scan(...) -> bf16
    scan_kernel<<<(B_ * (DI / 4)) / 4, blk, 0, stream>>>(
        dt, xc, xdbl, xz, A_log + (size_t)l * DI * DS, Dp + (size_t)l * DI,
        y16);
    // h += y @ w_out[l]  (MFMA, N=1024, K=2048)
    gemm_bt_mfma<1, 0><<<dim3(DM / 128, ROWS / 128), blk, 0, stream>>>(
        y16, woutT, nullptr, h, DI, DI, DI, DM);
  }

  final_kernel<<<B_, blk, 0, stream>>>(h, fnw, w_fc, b_fc, out);
}

// Round 3
// 1231.673 us; speedup vs baseline: 2.5204x; 1.3403x over previous
//
#include <hip/hip_runtime.h>
#include <hip/hip_bf16.h>
#include <math.h>

#define NL 4
#define DM 1024
#define DI 2048
#define DS 16
#define DR 64
#define DC 4
#define B_ 8
#define L_ 224
#define DLOC 672
#define NC 10
#define EPS 1e-5f

#define ROWS (B_ * L_)  // 1792

typedef unsigned short u16;
typedef __attribute__((ext_vector_type(8))) short bf16x8;
typedef __attribute__((ext_vector_type(4))) float f32x4;
typedef __attribute__((address_space(1))) const void gvoid_t;
typedef __attribute__((address_space(3))) void lvoid_t;

__device__ __forceinline__ u16 f2bf(float f) {
  union { float f; unsigned int u; } v;
  v.f = f;
  unsigned int u = v.u;
  return (u16)((u + 0x7fffu + ((u >> 16) & 1u)) >> 16);  // RNE
}

// ---------------------------------------------------------------------------
// bf16 MFMA GEMM (m97 structure): C[M,N] (+)= A[M,K]_bf16 @ B, with B given
// TRANSPOSED: Bt[N,K]_bf16. Tiles: 128x128 per block (256 thr = 4 waves,
// each wave 64x64 = 4x4 MFMA 16x16x32). Staging via global_load_lds width=16.
// Requires M%128==0, N%128==0, K%32==0.
// ---------------------------------------------------------------------------
template <int ACC, int BIAS>
__global__ __launch_bounds__(256) void gemm_bt_mfma(
    const u16* __restrict__ A, const u16* __restrict__ Bt,
    const float* __restrict__ bias, float* __restrict__ C, int K, int lda,
    int ldb, int ldc) {
  __shared__ __align__(16) u16 As[128 * 32];
  __shared__ __align__(16) u16 Bs[128 * 32];
  const int tid = threadIdx.x;
  const int lane = tid & 63;
  const int wv = tid >> 6;
  const int n0 = blockIdx.x * 128;
  const int m0 = blockIdx.y * 128;
  const int wm0 = (wv & 1) * 64;
  const int wn0 = (wv >> 1) * 64;
  const int quad = lane >> 4;
  const int l16 = lane & 15;

  const int srow = wv * 32 + (lane >> 2);
  const int scol = (lane & 3) * 8;
  const u16* ga0 = A + (size_t)(m0 + srow) * lda + scol;
  const u16* ga1 = ga0 + (size_t)16 * lda;
  const u16* gb0 = Bt + (size_t)(n0 + srow) * ldb + scol;
  const u16* gb1 = gb0 + (size_t)16 * ldb;
  u16* la0 = &As[(wv * 32) * 32];
  u16* la1 = &As[(wv * 32 + 16) * 32];
  u16* lb0 = &Bs[(wv * 32) * 32];
  u16* lb1 = &Bs[(wv * 32 + 16) * 32];

  f32x4 acc[4][4] = {};

  for (int k0 = 0; k0 < K; k0 += 32) {
    __syncthreads();
    __builtin_amdgcn_global_load_lds((gvoid_t*)ga0, (lvoid_t*)la0, 16, 0, 0);
    __builtin_amdgcn_global_load_lds((gvoid_t*)ga1, (lvoid_t*)la1, 16, 0, 0);
    __builtin_amdgcn_global_load_lds((gvoid_t*)gb0, (lvoid_t*)lb0, 16, 0, 0);
    __builtin_amdgcn_global_load_lds((gvoid_t*)gb1, (lvoid_t*)lb1, 16, 0, 0);
    __syncthreads();
    bf16x8 af[4], bfr[4];
#pragma unroll
    for (int i = 0; i < 4; i++)
      af[i] = *(const bf16x8*)&As[(wm0 + i * 16 + l16) * 32 + quad * 8];
#pragma unroll
    for (int j = 0; j < 4; j++)
      bfr[j] = *(const bf16x8*)&Bs[(wn0 + j * 16 + l16) * 32 + quad * 8];
#pragma unroll
    for (int i = 0; i < 4; i++)
#pragma unroll
      for (int j = 0; j < 4; j++)
        acc[i][j] = __builtin_amdgcn_mfma_f32_16x16x32_bf16(af[i], bfr[j],
                                                            acc[i][j], 0, 0, 0);
    ga0 += 32; ga1 += 32; gb0 += 32; gb1 += 32;
  }

#pragma unroll
  for (int i = 0; i < 4; i++) {
#pragma unroll
    for (int j = 0; j < 4; j++) {
      const int col = n0 + wn0 + j * 16 + l16;
      const int rowb = m0 + wm0 + i * 16 + quad * 4;
      float bv = 0.f;
      if (BIAS) bv = bias[col];
#pragma unroll
      for (int r = 0; r < 4; r++) {
        float v = acc[i][j][r] + bv;
        float* p = C + (size_t)(rowb + r) * ldc + col;
        if (ACC) v += *p;
        *p = v;
      }
    }
  }
}

// ---------------------------------------------------------------------------
// fp32 tiled GEMM (w_x split-K and dt). ACC: 0=store, 1=+=, 2=atomic.
// ---------------------------------------------------------------------------
template <int ACC, int ACT, int SPLITK>
__global__ __launch_bounds__(256) void gemm_kernel(
    const float* __restrict__ A, const float* __restrict__ Bm,
    const float* __restrict__ bias, float* __restrict__ C, int M, int N, int K,
    int lda, int ldb, int ldc) {
  if (SPLITK) {
    A += (size_t)blockIdx.z * 256;
    Bm += (size_t)blockIdx.z * 256 * ldb;
  }
  __shared__ float As[16][64];
  __shared__ float Bs[16][64];
  const int tid = threadIdx.x;
  const int tx = tid & 15;
  const int ty = tid >> 4;
  const int n0 = blockIdx.x * 64;
  const int m0 = blockIdx.y * 64;
  const int am = tid & 63;
  const int ak = (tid >> 6) * 4;
  const int bk = tid >> 4;
  const int bn = (tid & 15) * 4;

  float acc[4][4];
#pragma unroll
  for (int i = 0; i < 4; i++)
#pragma unroll
    for (int j = 0; j < 4; j++) acc[i][j] = 0.f;

  for (int k0 = 0; k0 < K; k0 += 16) {
    float4 av = *(const float4*)(A + (size_t)(m0 + am) * lda + k0 + ak);
    float4 bv;
    {
      int n = n0 + bn;
      const float* bp = Bm + (size_t)(k0 + bk) * ldb + n;
      if (n + 3 < N) {
        bv = *(const float4*)bp;
      } else {
        bv.x = (n + 0 < N) ? bp[0] : 0.f;
        bv.y = (n + 1 < N) ? bp[1] : 0.f;
        bv.z = (n + 2 < N) ? bp[2] : 0.f;
        bv.w = (n + 3 < N) ? bp[3] : 0.f;
      }
    }
    __syncthreads();
    As[ak + 0][am] = av.x;
    As[ak + 1][am] = av.y;
    As[ak + 2][am] = av.z;
    As[ak + 3][am] = av.w;
    *(float4*)(&Bs[bk][bn]) = bv;
    __syncthreads();
#pragma unroll
    for (int kk = 0; kk < 16; kk++) {
      float4 a4 = *(const float4*)(&As[kk][ty * 4]);
      float4 b4 = *(const float4*)(&Bs[kk][tx * 4]);
      float ar[4] = {a4.x, a4.y, a4.z, a4.w};
      float br[4] = {b4.x, b4.y, b4.z, b4.w};
#pragma unroll
      for (int i = 0; i < 4; i++)
#pragma unroll
        for (int j = 0; j < 4; j++) acc[i][j] = fmaf(ar[i], br[j], acc[i][j]);
    }
  }

#pragma unroll
  for (int i = 0; i < 4; i++) {
    int m = m0 + ty * 4 + i;
#pragma unroll
    for (int j = 0; j < 4; j++) {
      int n = n0 + tx * 4 + j;
      if (n < N) {
        float v = acc[i][j];
        if (bias) v += bias[n];
        if (ACT == 1) v = (v > 20.f) ? v : log1pf(expf(v));  // softplus
        float* p = C + (size_t)m * ldc + n;
        if (ACC == 2) {
          atomicAdd(p, v);
        } else {
          if (ACC == 1) v += *p;
          *p = v;
        }
      }
    }
  }
}

// ---------------------------------------------------------------------------
// fp32 [K,N] -> bf16 [N,K] transpose+convert, 32x32 LDS tiles
// ---------------------------------------------------------------------------
__global__ __launch_bounds__(256) void transpose_cvt_kernel(
    const float* __restrict__ src, u16* __restrict__ dst, int K, int N) {
  __shared__ float t[32][33];
  const int n0 = blockIdx.x * 32;
  const int k0 = blockIdx.y * 32;
  const int c = threadIdx.x & 31;
  const int r = threadIdx.x >> 5;  // 0..7
#pragma unroll
  for (int rr = 0; rr < 4; rr++)
    t[r + rr * 8][c] = src[(size_t)(k0 + r + rr * 8) * N + n0 + c];
  __syncthreads();
#pragma unroll
  for (int rr = 0; rr < 4; rr++)
    dst[(size_t)(n0 + r + rr * 8) * K + k0 + c] = f2bf(t[c][r + rr * 8]);
}

// flat fp32 -> bf16, 4 elems/thread
__global__ __launch_bounds__(256) void cvt_kernel(const float* __restrict__ src,
                                                  u16* __restrict__ dst) {
  const int i = blockIdx.x * 256 + threadIdx.x;
  const float4 v = ((const float4*)src)[i];
  ushort4 o;
  o.x = f2bf(v.x);
  o.y = f2bf(v.y);
  o.z = f2bf(v.z);
  o.w = f2bf(v.w);
  ((ushort4*)dst)[i] = o;
}

// ---------------------------------------------------------------------------
// RMSNorm -> bf16 out
// ---------------------------------------------------------------------------
__global__ __launch_bounds__(256) void rmsnorm_kernel(
    const float* __restrict__ h, const float* __restrict__ w,
    u16* __restrict__ out) {
  const int row = blockIdx.x;
  const int tid = threadIdx.x;
  const float4 v = *(const float4*)(h + (size_t)row * DM + tid * 4);
  float ss = v.x * v.x + v.y * v.y + v.z * v.z + v.w * v.w;
#pragma unroll
  for (int off = 32; off > 0; off >>= 1) ss += __shfl_xor(ss, off);
  __shared__ float red[4];
  if ((tid & 63) == 0) red[tid >> 6] = ss;
  __syncthreads();
  float tot = red[0] + red[1] + red[2] + red[3];
  const float inv = rsqrtf(tot / (float)DM + EPS);
  const float4 wv = *(const float4*)(w + tid * 4);
  ushort4 o;
  o.x = f2bf(v.x * inv * wv.x);
  o.y = f2bf(v.y * inv * wv.y);
  o.z = f2bf(v.z * inv * wv.z);
  o.w = f2bf(v.w * inv * wv.w);
  *(ushort4*)(out + (size_t)row * DM + tid * 4) = o;
}

// ---------------------------------------------------------------------------
// Causal depthwise conv (DC=4) + bias + silu (fp32 in/out)
// ---------------------------------------------------------------------------
__global__ __launch_bounds__(256) void conv_silu_kernel(
    const float* __restrict__ xz, const float* __restrict__ wc,
    const float* __restrict__ bc, float* __restrict__ xc) {
  const int idx = blockIdx.x * 256 + threadIdx.x;
  const int d = idx & (DI - 1);
  const int t = (idx / DI) % L_;
  const float w0 = wc[d * 4 + 0], w1 = wc[d * 4 + 1], w2 = wc[d * 4 + 2],
              w3 = wc[d * 4 + 3];
  const size_t base = (size_t)(idx / DI) * (2 * DI) + d;
  float s = bc[d];
  if (t >= 3) s += xz[base - 3 * (2 * DI)] * w0;
  if (t >= 2) s += xz[base - 2 * (2 * DI)] * w1;
  if (t >= 1) s += xz[base - 1 * (2 * DI)] * w2;
  s += xz[base] * w3;
  s = s / (1.f + expf(-s));
  xc[idx] = s;
}

// ---------------------------------------------------------------------------
// Selective scan v2: register-resident states, LDS-chunked streaming.
// One wave (64-thread block) per (b, 32-channel group).
// lane = (s_half<<5)|d_sub: each lane owns channel d0+d_sub, states
// s_half*8 .. s_half*8+7 in registers.
// Streams dt/xc/z/BC in 16-step chunks via global_load_lds, double-buffered.
// ---------------------------------------------------------------------------
#define T_CH 16
#define N_CH (L_ / T_CH)  // 14

__global__ __launch_bounds__(64) void scan_kernel(
    const float* __restrict__ dt, const float* __restrict__ xc,
    const float* __restrict__ xdbl, const float* __restrict__ xz,
    const float* __restrict__ A_log, const float* __restrict__ Dp,
    u16* __restrict__ y) {
  __shared__ __align__(16) float dtb[2][T_CH * 32];
  __shared__ __align__(16) float ub[2][T_CH * 32];
  __shared__ __align__(16) float zb[2][T_CH * 32];
  __shared__ __align__(16) float bcb[2][T_CH * 32];

  const int lane = threadIdx.x;        // 0..63
  const int b = blockIdx.x >> 6;       // 64 blocks per batch
  const int d0 = (blockIdx.x & 63) << 5;
  const int dsub = lane & 31;
  const int sh = lane >> 5;            // state half
  const int s0 = sh * 8;
  const int d = d0 + dsub;

  // staging lane mapping: instr i covers t_off = i*8 + (lane>>3), 8 lanes/row
  const int t_off = lane >> 3;         // 0..7
  const int c4 = (lane & 7) * 4;       // float col within 32

  float A2[8], hs[8];
  {
    float4 a0 = *(const float4*)(A_log + (size_t)d * DS + s0);
    float4 a1 = *(const float4*)(A_log + (size_t)d * DS + s0 + 4);
    const float k = -1.44269504f;  // -log2(e)
    A2[0] = expf(a0.x) * k; A2[1] = expf(a0.y) * k;
    A2[2] = expf(a0.z) * k; A2[3] = expf(a0.w) * k;
    A2[4] = expf(a1.x) * k; A2[5] = expf(a1.y) * k;
    A2[6] = expf(a1.z) * k; A2[7] = expf(a1.w) * k;
  }
#pragma unroll
  for (int j = 0; j < 8; j++) hs[j] = 0.f;
  const float Dpd = Dp[d];

  auto prefetch = [&](int c, int p) {
    const int rbase = b * L_ + c * T_CH + t_off;
#pragma unroll
    for (int i = 0; i < 2; i++) {
      const int r = rbase + i * 8;
      __builtin_amdgcn_global_load_lds(
          (gvoid_t*)(dt + (size_t)r * DI + d0 + c4),
          (lvoid_t*)((char*)&dtb[p][0] + i * 1024), 16, 0, 0);
      __builtin_amdgcn_global_load_lds(
          (gvoid_t*)(xc + (size_t)r * DI + d0 + c4),
          (lvoid_t*)((char*)&ub[p][0] + i * 1024), 16, 0, 0);
      __builtin_amdgcn_global_load_lds(
          (gvoid_t*)(xz + (size_t)r * 2 * DI + DI + d0 + c4),
          (lvoid_t*)((char*)&zb[p][0] + i * 1024), 16, 0, 0);
      __builtin_amdgcn_global_load_lds(
          (gvoid_t*)(xdbl + (size_t)r * 96 + 64 + c4),
          (lvoid_t*)((char*)&bcb[p][0] + i * 1024), 16, 0, 0);
    }
  };

  prefetch(0, 0);
  for (int c = 0; c < N_CH; c++) {
    const int p = c & 1;
    __builtin_amdgcn_s_waitcnt(0x0f70);  // vmcnt(0), ignore lgkm/exp
    __builtin_amdgcn_sched_barrier(0);
    if (c + 1 < N_CH) prefetch(c + 1, p ^ 1);
    const int rb = b * L_ + c * T_CH;
#pragma unroll 4
    for (int t = 0; t < T_CH; t++) {
      const float dtv = dtb[p][t * 32 + dsub];
      const float uv = ub[p][t * 32 + dsub];
      const float zv = zb[p][t * 32 + dsub];
      float Bv[8], Cv[8];
      *(float4*)&Bv[0] = *(const float4*)&bcb[p][t * 32 + s0];
      *(float4*)&Bv[4] = *(const float4*)&bcb[p][t * 32 + s0 + 4];
      *(float4*)&Cv[0] = *(const float4*)&bcb[p][t * 32 + 16 + s0];
      *(float4*)&Cv[4] = *(const float4*)&bcb[p][t * 32 + 16 + s0 + 4];
      const float du = dtv * uv;
      float acc = 0.f;
#pragma unroll
      for (int j = 0; j < 8; j++) {
        const float e = exp2f(dtv * A2[j]);
        hs[j] = fmaf(hs[j], e, du * Bv[j]);
        acc = fmaf(hs[j], Cv[j], acc);
      }
      acc += __shfl_xor(acc, 32);
      if (sh == 0) {
        float yv = acc + Dpd * uv;
        yv *= zv / (1.f + expf(-zv));
        y[(size_t)(rb + t) * DI + d] = f2bf(yv);
      }
    }
  }
}

// ---------------------------------------------------------------------------
// Final: rmsnorm(h[b, L-1, :]) @ w_fc + b_fc
// ---------------------------------------------------------------------------
__global__ __launch_bounds__(256) void final_kernel(
    const float* __restrict__ h, const float* __restrict__ fnw,
    const float* __restrict__ w_fc, const float* __restrict__ b_fc,
    float* __restrict__ out) {
  const int b = blockIdx.x;
  const int tid = threadIdx.x;
  const size_t row = ((size_t)b * L_ + (L_ - 1)) * DM;
  const float4 v = *(const float4*)(h + row + tid * 4);
  float ss = v.x * v.x + v.y * v.y + v.z * v.z + v.w * v.w;
#pragma unroll
  for (int off = 32; off > 0; off >>= 1) ss += __shfl_xor(ss, off);
  __shared__ float red[4];
  if ((tid & 63) == 0) red[tid >> 6] = ss;
  __syncthreads();
  float tot = red[0] + red[1] + red[2] + red[3];
  const float inv = rsqrtf(tot / (float)DM + EPS);
  const float4 wv = *(const float4*)(fnw + tid * 4);
  float hn[4] = {v.x * inv * wv.x, v.y * inv * wv.y, v.z * inv * wv.z,
                 v.w * inv * wv.w};
  float partial[NC];
#pragma unroll
  for (int j = 0; j < NC; j++) partial[j] = 0.f;
#pragma unroll
  for (int e = 0; e < 4; e++) {
    const int dd = tid * 4 + e;
#pragma unroll
    for (int j = 0; j < NC; j++)
      partial[j] = fmaf(hn[e], w_fc[dd * NC + j], partial[j]);
  }
  __shared__ float red2[256][NC];
  for (int j = 0; j < NC; j++) red2[tid][j] = partial[j];
  __syncthreads();
  for (int stride = 128; stride > 0; stride >>= 1) {
    if (tid < stride)
      for (int j = 0; j < NC; j++) red2[tid][j] += red2[tid + stride][j];
    __syncthreads();
  }
  if (tid < NC) out[b * NC + tid] = red2[0][tid] + b_fc[tid];
}

// ---------------------------------------------------------------------------
extern "C" void kernel_launch(void* const* d_in, const int* in_sizes, int n_in,
                              void* d_out, int out_size, void* d_ws,
                              size_t ws_size, hipStream_t stream) {
  const float* x = (const float*)d_in[0];
  const float* w_proj = (const float*)d_in[1];
  const float* b_proj = (const float*)d_in[2];
  const float* norm_w = (const float*)d_in[3];
  const float* w_in = (const float*)d_in[4];
  const float* w_conv = (const float*)d_in[5];
  const float* b_conv = (const float*)d_in[6];
  const float* w_x = (const float*)d_in[7];
  const float* w_dt = (const float*)d_in[8];
  const float* b_dt = (const float*)d_in[9];
  const float* A_log = (const float*)d_in[10];
  const float* Dp = (const float*)d_in[11];
  const float* w_out = (const float*)d_in[12];
  const float* fnw = (const float*)d_in[13];
  const float* w_fc = (const float*)d_in[14];
  const float* b_fc = (const float*)d_in[15];
  float* out = (float*)d_out;

  // Workspace layout (float units)
  float* ws = (float*)d_ws;
  float* h = ws;                       // 1,835,008 f
  float* xz = h + 1835008;             // 7,340,032 f
  float* xc = xz + 7340032;            // 3,670,016 f
  float* xdbl = xc + 3670016;          //   172,032 f
  float* dt = xdbl + 172032;           // 3,670,016 f
  u16* y16 = (u16*)(dt + 3670016);     // 3,670,016 bf16 (1,835,008 f)
  u16* xn16 = y16;                     // alias (disjoint liveness)
  u16* x16 = (u16*)(dt + 3670016 + 1835008);      // 1,204,224 bf16
  u16* wprojT = (u16*)(dt + 3670016 + 2437120);   //   688,128 bf16
  u16* winT = (u16*)(dt + 3670016 + 2781184);     // 4,194,304 bf16
  u16* woutT = (u16*)(dt + 3670016 + 4878336);    // 2,097,152 bf16

  const dim3 blk(256);

  cvt_kernel<<<ROWS * DLOC / 1024, blk, 0, stream>>>(x, x16);
  transpose_cvt_kernel<<<dim3(DM / 32, DLOC / 32), blk, 0, stream>>>(
      w_proj, wprojT, DLOC, DM);

  // h = x @ w_proj + b_proj (bf16 MFMA)
  gemm_bt_mfma<0, 1><<<dim3(DM / 128, ROWS / 128), blk, 0, stream>>>(
      x16, wprojT, b_proj, h, DLOC, DLOC, DLOC, DM);

  for (int l = 0; l < NL; l++) {
    transpose_cvt_kernel<<<dim3(2 * DI / 32, DM / 32), blk, 0, stream>>>(
        w_in + (size_t)l * DM * 2 * DI, winT, DM, 2 * DI);
    transpose_cvt_kernel<<<dim3(DM / 32, DI / 32), blk, 0, stream>>>(
        w_out + (size_t)l * DI * DM, woutT, DI, DM);

    rmsnorm_kernel<<<ROWS, blk, 0, stream>>>(h, norm_w + (size_t)l * DM, xn16);
    // xz = xn @ w_in[l]  (MFMA, N=4096, K=1024)
    gemm_bt_mfma<0, 0><<<dim3(2 * DI / 128, ROWS / 128), blk, 0, stream>>>(
        xn16, winT, nullptr, xz, DM, DM, DM, 2 * DI);
    conv_silu_kernel<<<ROWS * DI / 256, blk, 0, stream>>>(
        xz, w_conv + (size_t)l * DI * DC, b_conv + (size_t)l * DI, xc);
    // xdbl = xc @ w_x[l]  (fp32 split-K x8 + atomics)
    hipMemsetAsync(xdbl, 0, (size_t)ROWS * 96 * sizeof(float), stream);
    gemm_kernel<2, 0, 1><<<dim3(2, ROWS / 64, 8), blk, 0, stream>>>(
        xc, w_x + (size_t)l * DI * 96, nullptr, xdbl, ROWS, 96, 256, DI, 96,
        96);
    // dt = softplus(dtr @ w_dt[l] + b_dt[l])  (fp32, K=64)
    gemm_kernel<0, 1, 0><<<dim3(DI / 64, ROWS / 64), blk, 0, stream>>>(
        xdbl, w_dt + (size_t)l * DR * DI, b_dt + (size_t)l * DI, dt, ROWS, DI,
        DR, 96, DI, DI);
    // y = scan(...) -> bf16  (512 one-wave blocks)
    scan_kernel<<<B_ * (DI / 32), dim3(64), 0, stream>>>(
        dt, xc, xdbl, xz, A_log + (size_t)l * DI * DS, Dp + (size_t)l * DI,
        y16);
    // h += y @ w_out[l]  (MFMA, N=1024, K=2048)
    gemm_bt_mfma<1, 0><<<dim3(DM / 128, ROWS / 128), blk, 0, stream>>>(
        y16, woutT, nullptr, h, DI, DI, DI, DM);
  }

  final_kernel<<<B_, blk, 0, stream>>>(h, fnw, w_fc, b_fc, out);
}

// Round 4
// 1210.302 us; speedup vs baseline: 2.5649x; 1.0177x over previous
//
#include <hip/hip_runtime.h>
#include <hip/hip_bf16.h>
#include <math.h>

#define NL 4
#define DM 1024
#define DI 2048
#define DS 16
#define DR 64
#define DC 4
#define B_ 8
#define L_ 224
#define DLOC 672
#define NC 10
#define EPS 1e-5f

#define ROWS (B_ * L_)  // 1792

typedef unsigned short u16;
typedef __attribute__((ext_vector_type(8))) short bf16x8;
typedef __attribute__((ext_vector_type(4))) float f32x4;
typedef __attribute__((address_space(1))) const void gvoid_t;
typedef __attribute__((address_space(3))) void lvoid_t;

__device__ __forceinline__ u16 f2bf(float f) {
  union { float f; unsigned int u; } v;
  v.f = f;
  unsigned int u = v.u;
  return (u16)((u + 0x7fffu + ((u >> 16) & 1u)) >> 16);  // RNE
}

// ---------------------------------------------------------------------------
// bf16 MFMA GEMM (m97 structure): C[M,N] (+)= A[M,K]_bf16 @ B, with B given
// TRANSPOSED: Bt[N,K]_bf16. Tiles: 128x128 per block (256 thr = 4 waves,
// each wave 64x64 = 4x4 MFMA 16x16x32). Staging via global_load_lds width=16.
// Requires M%128==0, N%128==0, K%32==0.
// ---------------------------------------------------------------------------
template <int ACC, int BIAS>
__global__ __launch_bounds__(256) void gemm_bt_mfma(
    const u16* __restrict__ A, const u16* __restrict__ Bt,
    const float* __restrict__ bias, float* __restrict__ C, int K, int lda,
    int ldb, int ldc) {
  __shared__ __align__(16) u16 As[128 * 32];
  __shared__ __align__(16) u16 Bs[128 * 32];
  const int tid = threadIdx.x;
  const int lane = tid & 63;
  const int wv = tid >> 6;
  const int n0 = blockIdx.x * 128;
  const int m0 = blockIdx.y * 128;
  const int wm0 = (wv & 1) * 64;
  const int wn0 = (wv >> 1) * 64;
  const int quad = lane >> 4;
  const int l16 = lane & 15;

  const int srow = wv * 32 + (lane >> 2);
  const int scol = (lane & 3) * 8;
  const u16* ga0 = A + (size_t)(m0 + srow) * lda + scol;
  const u16* ga1 = ga0 + (size_t)16 * lda;
  const u16* gb0 = Bt + (size_t)(n0 + srow) * ldb + scol;
  const u16* gb1 = gb0 + (size_t)16 * ldb;
  u16* la0 = &As[(wv * 32) * 32];
  u16* la1 = &As[(wv * 32 + 16) * 32];
  u16* lb0 = &Bs[(wv * 32) * 32];
  u16* lb1 = &Bs[(wv * 32 + 16) * 32];

  f32x4 acc[4][4] = {};

  for (int k0 = 0; k0 < K; k0 += 32) {
    __syncthreads();
    __builtin_amdgcn_global_load_lds((gvoid_t*)ga0, (lvoid_t*)la0, 16, 0, 0);
    __builtin_amdgcn_global_load_lds((gvoid_t*)ga1, (lvoid_t*)la1, 16, 0, 0);
    __builtin_amdgcn_global_load_lds((gvoid_t*)gb0, (lvoid_t*)lb0, 16, 0, 0);
    __builtin_amdgcn_global_load_lds((gvoid_t*)gb1, (lvoid_t*)lb1, 16, 0, 0);
    __syncthreads();
    bf16x8 af[4], bfr[4];
#pragma unroll
    for (int i = 0; i < 4; i++)
      af[i] = *(const bf16x8*)&As[(wm0 + i * 16 + l16) * 32 + quad * 8];
#pragma unroll
    for (int j = 0; j < 4; j++)
      bfr[j] = *(const bf16x8*)&Bs[(wn0 + j * 16 + l16) * 32 + quad * 8];
#pragma unroll
    for (int i = 0; i < 4; i++)
#pragma unroll
      for (int j = 0; j < 4; j++)
        acc[i][j] = __builtin_amdgcn_mfma_f32_16x16x32_bf16(af[i], bfr[j],
                                                            acc[i][j], 0, 0, 0);
    ga0 += 32; ga1 += 32; gb0 += 32; gb1 += 32;
  }

#pragma unroll
  for (int i = 0; i < 4; i++) {
#pragma unroll
    for (int j = 0; j < 4; j++) {
      const int col = n0 + wn0 + j * 16 + l16;
      const int rowb = m0 + wm0 + i * 16 + quad * 4;
      float bv = 0.f;
      if (BIAS) bv = bias[col];
#pragma unroll
      for (int r = 0; r < 4; r++) {
        float v = acc[i][j][r] + bv;
        float* p = C + (size_t)(rowb + r) * ldc + col;
        if (ACC) v += *p;
        *p = v;
      }
    }
  }
}

// ---------------------------------------------------------------------------
// fp32 tiled GEMM (w_x split-K and dt). ACC: 0=store, 1=+=, 2=atomic.
// ---------------------------------------------------------------------------
template <int ACC, int ACT, int SPLITK>
__global__ __launch_bounds__(256) void gemm_kernel(
    const float* __restrict__ A, const float* __restrict__ Bm,
    const float* __restrict__ bias, float* __restrict__ C, int M, int N, int K,
    int lda, int ldb, int ldc) {
  if (SPLITK) {
    A += (size_t)blockIdx.z * 256;
    Bm += (size_t)blockIdx.z * 256 * ldb;
  }
  __shared__ float As[16][64];
  __shared__ float Bs[16][64];
  const int tid = threadIdx.x;
  const int tx = tid & 15;
  const int ty = tid >> 4;
  const int n0 = blockIdx.x * 64;
  const int m0 = blockIdx.y * 64;
  const int am = tid & 63;
  const int ak = (tid >> 6) * 4;
  const int bk = tid >> 4;
  const int bn = (tid & 15) * 4;

  float acc[4][4];
#pragma unroll
  for (int i = 0; i < 4; i++)
#pragma unroll
    for (int j = 0; j < 4; j++) acc[i][j] = 0.f;

  for (int k0 = 0; k0 < K; k0 += 16) {
    float4 av = *(const float4*)(A + (size_t)(m0 + am) * lda + k0 + ak);
    float4 bv;
    {
      int n = n0 + bn;
      const float* bp = Bm + (size_t)(k0 + bk) * ldb + n;
      if (n + 3 < N) {
        bv = *(const float4*)bp;
      } else {
        bv.x = (n + 0 < N) ? bp[0] : 0.f;
        bv.y = (n + 1 < N) ? bp[1] : 0.f;
        bv.z = (n + 2 < N) ? bp[2] : 0.f;
        bv.w = (n + 3 < N) ? bp[3] : 0.f;
      }
    }
    __syncthreads();
    As[ak + 0][am] = av.x;
    As[ak + 1][am] = av.y;
    As[ak + 2][am] = av.z;
    As[ak + 3][am] = av.w;
    *(float4*)(&Bs[bk][bn]) = bv;
    __syncthreads();
#pragma unroll
    for (int kk = 0; kk < 16; kk++) {
      float4 a4 = *(const float4*)(&As[kk][ty * 4]);
      float4 b4 = *(const float4*)(&Bs[kk][tx * 4]);
      float ar[4] = {a4.x, a4.y, a4.z, a4.w};
      float br[4] = {b4.x, b4.y, b4.z, b4.w};
#pragma unroll
      for (int i = 0; i < 4; i++)
#pragma unroll
        for (int j = 0; j < 4; j++) acc[i][j] = fmaf(ar[i], br[j], acc[i][j]);
    }
  }

#pragma unroll
  for (int i = 0; i < 4; i++) {
    int m = m0 + ty * 4 + i;
#pragma unroll
    for (int j = 0; j < 4; j++) {
      int n = n0 + tx * 4 + j;
      if (n < N) {
        float v = acc[i][j];
        if (bias) v += bias[n];
        if (ACT == 1) v = (v > 20.f) ? v : log1pf(expf(v));  // softplus
        float* p = C + (size_t)m * ldc + n;
        if (ACC == 2) {
          atomicAdd(p, v);
        } else {
          if (ACC == 1) v += *p;
          *p = v;
        }
      }
    }
  }
}

// ---------------------------------------------------------------------------
// fp32 [K,N] -> bf16 [N,K] transpose+convert, 32x32 LDS tiles
// ---------------------------------------------------------------------------
__global__ __launch_bounds__(256) void transpose_cvt_kernel(
    const float* __restrict__ src, u16* __restrict__ dst, int K, int N) {
  __shared__ float t[32][33];
  const int n0 = blockIdx.x * 32;
  const int k0 = blockIdx.y * 32;
  const int c = threadIdx.x & 31;
  const int r = threadIdx.x >> 5;  // 0..7
#pragma unroll
  for (int rr = 0; rr < 4; rr++)
    t[r + rr * 8][c] = src[(size_t)(k0 + r + rr * 8) * N + n0 + c];
  __syncthreads();
#pragma unroll
  for (int rr = 0; rr < 4; rr++)
    dst[(size_t)(n0 + r + rr * 8) * K + k0 + c] = f2bf(t[c][r + rr * 8]);
}

// flat fp32 -> bf16, 4 elems/thread
__global__ __launch_bounds__(256) void cvt_kernel(const float* __restrict__ src,
                                                  u16* __restrict__ dst) {
  const int i = blockIdx.x * 256 + threadIdx.x;
  const float4 v = ((const float4*)src)[i];
  ushort4 o;
  o.x = f2bf(v.x);
  o.y = f2bf(v.y);
  o.z = f2bf(v.z);
  o.w = f2bf(v.w);
  ((ushort4*)dst)[i] = o;
}

// ---------------------------------------------------------------------------
// RMSNorm -> bf16 out
// ---------------------------------------------------------------------------
__global__ __launch_bounds__(256) void rmsnorm_kernel(
    const float* __restrict__ h, const float* __restrict__ w,
    u16* __restrict__ out) {
  const int row = blockIdx.x;
  const int tid = threadIdx.x;
  const float4 v = *(const float4*)(h + (size_t)row * DM + tid * 4);
  float ss = v.x * v.x + v.y * v.y + v.z * v.z + v.w * v.w;
#pragma unroll
  for (int off = 32; off > 0; off >>= 1) ss += __shfl_xor(ss, off);
  __shared__ float red[4];
  if ((tid & 63) == 0) red[tid >> 6] = ss;
  __syncthreads();
  float tot = red[0] + red[1] + red[2] + red[3];
  const float inv = rsqrtf(tot / (float)DM + EPS);
  const float4 wv = *(const float4*)(w + tid * 4);
  ushort4 o;
  o.x = f2bf(v.x * inv * wv.x);
  o.y = f2bf(v.y * inv * wv.y);
  o.z = f2bf(v.z * inv * wv.z);
  o.w = f2bf(v.w * inv * wv.w);
  *(ushort4*)(out + (size_t)row * DM + tid * 4) = o;
}

// ---------------------------------------------------------------------------
// Causal depthwise conv (DC=4) + bias + silu (fp32 in/out)
// ---------------------------------------------------------------------------
__global__ __launch_bounds__(256) void conv_silu_kernel(
    const float* __restrict__ xz, const float* __restrict__ wc,
    const float* __restrict__ bc, float* __restrict__ xc) {
  const int idx = blockIdx.x * 256 + threadIdx.x;
  const int d = idx & (DI - 1);
  const int t = (idx / DI) % L_;
  const float w0 = wc[d * 4 + 0], w1 = wc[d * 4 + 1], w2 = wc[d * 4 + 2],
              w3 = wc[d * 4 + 3];
  const size_t base = (size_t)(idx / DI) * (2 * DI) + d;
  float s = bc[d];
  if (t >= 3) s += xz[base - 3 * (2 * DI)] * w0;
  if (t >= 2) s += xz[base - 2 * (2 * DI)] * w1;
  if (t >= 1) s += xz[base - 1 * (2 * DI)] * w2;
  s += xz[base] * w3;
  s = s / (1.f + expf(-s));
  xc[idx] = s;
}

// ---------------------------------------------------------------------------
// Selective scan v3: 8 channels/wave, 2 states/lane -> 2048 waves (8/CU).
// lane = (c<<3)|sg: channel d0+c, states {2sg, 2sg+1} in registers.
// Reduction over sg: 3 shfl_xor. LDS-chunked double-buffered streaming via
// global_load_lds (width 4 for dt/u/z, width 16 for B/C).
// ---------------------------------------------------------------------------
#define T_CH 16
#define N_CH (L_ / T_CH)  // 14

__global__ __launch_bounds__(64) void scan_kernel(
    const float* __restrict__ dt, const float* __restrict__ xc,
    const float* __restrict__ xdbl, const float* __restrict__ xz,
    const float* __restrict__ A_log, const float* __restrict__ Dp,
    u16* __restrict__ y) {
  __shared__ __align__(16) float dtb[2][T_CH * 8];
  __shared__ __align__(16) float ub[2][T_CH * 8];
  __shared__ __align__(16) float zb[2][T_CH * 8];
  __shared__ __align__(16) float bcb[2][T_CH * 32];

  const int lane = threadIdx.x;        // 0..63
  const int b = blockIdx.x >> 8;       // 256 blocks per batch
  const int d0 = (blockIdx.x & 255) << 3;
  const int c = lane >> 3;             // channel within group
  const int sg = lane & 7;             // state pair index
  const int d = d0 + c;
  const int s0 = sg * 2;

  // staging lane mappings (all 64 lanes):
  const int t8 = lane >> 3;            // 0..7 (row within half-chunk)
  const int c8 = lane & 7;             // dt/u/z: channel col
  const int f4 = (lane & 7) * 4;       // bc: float col within 32

  float A20, A21, hs0 = 0.f, hs1 = 0.f;
  {
    float2 a = *(const float2*)(A_log + (size_t)d * DS + s0);
    const float k = -1.44269504f;  // -log2(e)
    A20 = expf(a.x) * k;
    A21 = expf(a.y) * k;
  }
  const float Dpd = Dp[d];

  auto prefetch = [&](int ch, int pp) {
    const int rbase = b * L_ + ch * T_CH + t8;
#pragma unroll
    for (int i = 0; i < 2; i++) {
      const int r = rbase + i * 8;
      __builtin_amdgcn_global_load_lds(
          (gvoid_t*)(dt + (size_t)r * DI + d0 + c8),
          (lvoid_t*)((char*)&dtb[pp][0] + i * 256), 4, 0, 0);
      __builtin_amdgcn_global_load_lds(
          (gvoid_t*)(xc + (size_t)r * DI + d0 + c8),
          (lvoid_t*)((char*)&ub[pp][0] + i * 256), 4, 0, 0);
      __builtin_amdgcn_global_load_lds(
          (gvoid_t*)(xz + (size_t)r * 2 * DI + DI + d0 + c8),
          (lvoid_t*)((char*)&zb[pp][0] + i * 256), 4, 0, 0);
      __builtin_amdgcn_global_load_lds(
          (gvoid_t*)(xdbl + (size_t)r * 96 + 64 + f4),
          (lvoid_t*)((char*)&bcb[pp][0] + i * 1024), 16, 0, 0);
    }
  };

  prefetch(0, 0);
  for (int ch = 0; ch < N_CH; ch++) {
    const int p = ch & 1;
    __builtin_amdgcn_s_waitcnt(0x0f70);  // vmcnt(0)
    __builtin_amdgcn_sched_barrier(0);
    if (ch + 1 < N_CH) prefetch(ch + 1, p ^ 1);
    const int rb = b * L_ + ch * T_CH;
#pragma unroll
    for (int t = 0; t < T_CH; t++) {
      const float dtv = dtb[p][t * 8 + c];
      const float uv = ub[p][t * 8 + c];
      const float2 Bp = *(const float2*)&bcb[p][t * 32 + s0];
      const float2 Cp = *(const float2*)&bcb[p][t * 32 + 16 + s0];
      const float du = dtv * uv;
      const float e0 = exp2f(dtv * A20);
      const float e1 = exp2f(dtv * A21);
      hs0 = fmaf(hs0, e0, du * Bp.x);
      hs1 = fmaf(hs1, e1, du * Bp.y);
      float pr = fmaf(hs1, Cp.y, hs0 * Cp.x);
      pr += __shfl_xor(pr, 1);
      pr += __shfl_xor(pr, 2);
      pr += __shfl_xor(pr, 4);
      if (sg == 0) {
        const float zv = zb[p][t * 8 + c];
        float yv = pr + Dpd * uv;
        yv *= zv / (1.f + expf(-zv));
        y[(size_t)(rb + t) * DI + d] = f2bf(yv);
      }
    }
  }
}

// ---------------------------------------------------------------------------
// Final: rmsnorm(h[b, L-1, :]) @ w_fc + b_fc
// ---------------------------------------------------------------------------
__global__ __launch_bounds__(256) void final_kernel(
    const float* __restrict__ h, const float* __restrict__ fnw,
    const float* __restrict__ w_fc, const float* __restrict__ b_fc,
    float* __restrict__ out) {
  const int b = blockIdx.x;
  const int tid = threadIdx.x;
  const size_t row = ((size_t)b * L_ + (L_ - 1)) * DM;
  const float4 v = *(const float4*)(h + row + tid * 4);
  float ss = v.x * v.x + v.y * v.y + v.z * v.z + v.w * v.w;
#pragma unroll
  for (int off = 32; off > 0; off >>= 1) ss += __shfl_xor(ss, off);
  __shared__ float red[4];
  if ((tid & 63) == 0) red[tid >> 6] = ss;
  __syncthreads();
  float tot = red[0] + red[1] + red[2] + red[3];
  const float inv = rsqrtf(tot / (float)DM + EPS);
  const float4 wv = *(const float4*)(fnw + tid * 4);
  float hn[4] = {v.x * inv * wv.x, v.y * inv * wv.y, v.z * inv * wv.z,
                 v.w * inv * wv.w};
  float partial[NC];
#pragma unroll
  for (int j = 0; j < NC; j++) partial[j] = 0.f;
#pragma unroll
  for (int e = 0; e < 4; e++) {
    const int dd = tid * 4 + e;
#pragma unroll
    for (int j = 0; j < NC; j++)
      partial[j] = fmaf(hn[e], w_fc[dd * NC + j], partial[j]);
  }
  __shared__ float red2[256][NC];
  for (int j = 0; j < NC; j++) red2[tid][j] = partial[j];
  __syncthreads();
  for (int stride = 128; stride > 0; stride >>= 1) {
    if (tid < stride)
      for (int j = 0; j < NC; j++) red2[tid][j] += red2[tid + stride][j];
    __syncthreads();
  }
  if (tid < NC) out[b * NC + tid] = red2[0][tid] + b_fc[tid];
}

// ---------------------------------------------------------------------------
extern "C" void kernel_launch(void* const* d_in, const int* in_sizes, int n_in,
                              void* d_out, int out_size, void* d_ws,
                              size_t ws_size, hipStream_t stream) {
  const float* x = (const float*)d_in[0];
  const float* w_proj = (const float*)d_in[1];
  const float* b_proj = (const float*)d_in[2];
  const float* norm_w = (const float*)d_in[3];
  const float* w_in = (const float*)d_in[4];
  const float* w_conv = (const float*)d_in[5];
  const float* b_conv = (const float*)d_in[6];
  const float* w_x = (const float*)d_in[7];
  const float* w_dt = (const float*)d_in[8];
  const float* b_dt = (const float*)d_in[9];
  const float* A_log = (const float*)d_in[10];
  const float* Dp = (const float*)d_in[11];
  const float* w_out = (const float*)d_in[12];
  const float* fnw = (const float*)d_in[13];
  const float* w_fc = (const float*)d_in[14];
  const float* b_fc = (const float*)d_in[15];
  float* out = (float*)d_out;

  // Workspace layout (float units)
  float* ws = (float*)d_ws;
  float* h = ws;                       // 1,835,008 f
  float* xz = h + 1835008;             // 7,340,032 f
  float* xc = xz + 7340032;            // 3,670,016 f
  float* xdbl = xc + 3670016;          //   172,032 f
  float* dt = xdbl + 172032;           // 3,670,016 f
  u16* y16 = (u16*)(dt + 3670016);     // 3,670,016 bf16 (1,835,008 f)
  u16* xn16 = y16;                     // alias (disjoint liveness)
  u16* x16 = (u16*)(dt + 3670016 + 1835008);      // 1,204,224 bf16
  u16* wprojT = (u16*)(dt + 3670016 + 2437120);   //   688,128 bf16
  u16* winT = (u16*)(dt + 3670016 + 2781184);     // 4,194,304 bf16
  u16* woutT = (u16*)(dt + 3670016 + 4878336);    // 2,097,152 bf16

  const dim3 blk(256);

  cvt_kernel<<<ROWS * DLOC / 1024, blk, 0, stream>>>(x, x16);
  transpose_cvt_kernel<<<dim3(DM / 32, DLOC / 32), blk, 0, stream>>>(
      w_proj, wprojT, DLOC, DM);

  // h = x @ w_proj + b_proj (bf16 MFMA)
  gemm_bt_mfma<0, 1><<<dim3(DM / 128, ROWS / 128), blk, 0, stream>>>(
      x16, wprojT, b_proj, h, DLOC, DLOC, DLOC, DM);

  for (int l = 0; l < NL; l++) {
    transpose_cvt_kernel<<<dim3(2 * DI / 32, DM / 32), blk, 0, stream>>>(
        w_in + (size_t)l * DM * 2 * DI, winT, DM, 2 * DI);
    transpose_cvt_kernel<<<dim3(DM / 32, DI / 32), blk, 0, stream>>>(
        w_out + (size_t)l * DI * DM, woutT, DI, DM);

    rmsnorm_kernel<<<ROWS, blk, 0, stream>>>(h, norm_w + (size_t)l * DM, xn16);
    // xz = xn @ w_in[l]  (MFMA, N=4096, K=1024)
    gemm_bt_mfma<0, 0><<<dim3(2 * DI / 128, ROWS / 128), blk, 0, stream>>>(
        xn16, winT, nullptr, xz, DM, DM, DM, 2 * DI);
    conv_silu_kernel<<<ROWS * DI / 256, blk, 0, stream>>>(
        xz, w_conv + (size_t)l * DI * DC, b_conv + (size_t)l * DI, xc);
    // xdbl = xc @ w_x[l]  (fp32 split-K x8 + atomics)
    hipMemsetAsync(xdbl, 0, (size_t)ROWS * 96 * sizeof(float), stream);
    gemm_kernel<2, 0, 1><<<dim3(2, ROWS / 64, 8), blk, 0, stream>>>(
        xc, w_x + (size_t)l * DI * 96, nullptr, xdbl, ROWS, 96, 256, DI, 96,
        96);
    // dt = softplus(dtr @ w_dt[l] + b_dt[l])  (fp32, K=64)
    gemm_kernel<0, 1, 0><<<dim3(DI / 64, ROWS / 64), blk, 0, stream>>>(
        xdbl, w_dt + (size_t)l * DR * DI, b_dt + (size_t)l * DI, dt, ROWS, DI,
        DR, 96, DI, DI);
    // y = scan(...) -> bf16  (2048 one-wave blocks, 8 ch/wave)
    scan_kernel<<<B_ * (DI / 8), dim3(64), 0, stream>>>(
        dt, xc, xdbl, xz, A_log + (size_t)l * DI * DS, Dp + (size_t)l * DI,
        y16);
    // h += y @ w_out[l]  (MFMA, N=1024, K=2048)
    gemm_bt_mfma<1, 0><<<dim3(DM / 128, ROWS / 128), blk, 0, stream>>>(
        y16, woutT, nullptr, h, DI, DI, DI, DM);
  }

  final_kernel<<<B_, blk, 0, stream>>>(h, fnw, w_fc, b_fc, out);
}